// Round 1
// baseline (11737.595 us; speedup 1.0000x reference)
//
#include <hip/hip_runtime.h>
#include <math.h>

// Problem constants (fixed by reference)
#define BB   4
#define SS   4096
#define DD   1024
#define HH   16
#define HDIM 64
#define CC   1024      // MAX_CHUNKS
#define DFF  4096
#define LL   4

static constexpr float F32_EPS = 1.1920928955078125e-07f;  // jnp.finfo(f32).eps

// ---------------- RoPE tables: cos/sin[pos][i], i in [0,32) ----------------
__global__ void rope_init_kernel(float* __restrict__ cosT, float* __restrict__ sinT) {
    int idx = blockIdx.x * blockDim.x + threadIdx.x;   // over CC*32
    int pos = idx >> 5;
    int i   = idx & 31;
    float inv = powf(10000.0f, -(float)i / 32.0f);     // 1/10000^(2i/64)
    float f = (float)pos * inv;
    cosT[idx] = cosf(f);
    sinT[idx] = sinf(f);
}

// ---------------- boundary scan -> chunk starts, num_chunks ----------------
__global__ __launch_bounds__(1024) void scan_kernel(const int* __restrict__ boundary,
                                                    int* __restrict__ starts,
                                                    int* __restrict__ nch) {
    __shared__ int tmp[1024];
    int b = blockIdx.x, t = threadIdx.x;
    int base = b * SS + t * 4;
    int v0 = boundary[base + 0], v1 = boundary[base + 1];
    int v2 = boundary[base + 2], v3 = boundary[base + 3];
    int p0 = v0, p1 = p0 + v1, p2 = p1 + v2, p3 = p2 + v3;
    tmp[t] = p3;
    __syncthreads();
    for (int off = 1; off < 1024; off <<= 1) {
        int add = (t >= off) ? tmp[t - off] : 0;
        __syncthreads();
        tmp[t] += add;
        __syncthreads();
    }
    int excl = tmp[t] - p3;
    // inclusive cumsum - 1 = chunk id at each position
    if (v0) starts[b * (CC + 1) + (excl + p0 - 1)] = t * 4 + 0;
    if (v1) starts[b * (CC + 1) + (excl + p1 - 1)] = t * 4 + 1;
    if (v2) starts[b * (CC + 1) + (excl + p2 - 1)] = t * 4 + 2;
    if (v3) starts[b * (CC + 1) + (excl + p3 - 1)] = t * 4 + 3;
    int total = tmp[1023];
    if (t == 0) nch[b] = total;
    // chunks >= total (and the end sentinel) -> start = SS
    for (int c = t; c <= CC; c += 1024)
        if (c >= total) starts[b * (CC + 1) + c] = SS;
}

// ---------------- chunk means -> h and x0 ----------------
__global__ __launch_bounds__(256) void latents_kernel(const float* __restrict__ x,
                                                      const int* __restrict__ starts,
                                                      float* __restrict__ h,
                                                      float* __restrict__ x0) {
    int c = blockIdx.x, b = blockIdx.y, t = threadIdx.x;
    int s0 = starts[b * (CC + 1) + c];
    int s1 = starts[b * (CC + 1) + c + 1];
    float a0 = 0.f, a1 = 0.f, a2 = 0.f, a3 = 0.f;
    for (int r = s0; r < s1; ++r) {
        const float4 xv = *(const float4*)&x[((size_t)(b * SS + r)) * DD + t * 4];
        a0 += xv.x; a1 += xv.y; a2 += xv.z; a3 += xv.w;
    }
    float inv = (s1 > s0) ? 1.0f / (float)(s1 - s0) : 0.0f;
    float4 o = make_float4(a0 * inv, a1 * inv, a2 * inv, a3 * inv);
    size_t off = ((size_t)(b * CC + c)) * DD + t * 4;
    *(float4*)&h[off]  = o;
    *(float4*)&x0[off] = o;
}

// ---------------- optional resid-mix + row RMS norm ----------------
// mix != nullptr: hnew = mix0*h + mix1*x0, store hnew to hout; xn = rms(hnew)
// mix == nullptr: xn = rms(h) (h untouched)
__global__ __launch_bounds__(256) void rmsmix_kernel(const float* __restrict__ hin,
                                                     const float* __restrict__ x0,
                                                     const float* __restrict__ mix,
                                                     float* __restrict__ hout,
                                                     float* __restrict__ xnout) {
    int row = blockIdx.x, t = threadIdx.x;
    size_t off = (size_t)row * DD + t * 4;
    float4 hv = *(const float4*)&hin[off];
    if (mix) {
        float4 m0 = *(const float4*)&mix[t * 4];
        float4 m1 = *(const float4*)&mix[DD + t * 4];
        float4 xv = *(const float4*)&x0[off];
        hv.x = m0.x * hv.x + m1.x * xv.x;
        hv.y = m0.y * hv.y + m1.y * xv.y;
        hv.z = m0.z * hv.z + m1.z * xv.z;
        hv.w = m0.w * hv.w + m1.w * xv.w;
    }
    float ss = hv.x * hv.x + hv.y * hv.y + hv.z * hv.z + hv.w * hv.w;
    for (int o = 32; o; o >>= 1) ss += __shfl_xor(ss, o);
    __shared__ float wsum[4];
    int lane = t & 63, wid = t >> 6;
    if (lane == 0) wsum[wid] = ss;
    __syncthreads();
    float tot = wsum[0] + wsum[1] + wsum[2] + wsum[3];
    float r = rsqrtf(tot * (1.0f / DD) + F32_EPS);
    if (hout) *(float4*)&hout[off] = hv;
    float4 xo = make_float4(hv.x * r, hv.y * r, hv.z * r, hv.w * r);
    *(float4*)&xnout[off] = xo;
}

// ---------------- f32 GEMM: C[M,N] = A[M,K] @ W[N,K]^T ----------------
// EPI: 0 = plain store, 1 = relu(x)^2
template <int EPI>
__global__ __launch_bounds__(256) void gemm_kernel(const float* __restrict__ A,
                                                   const float* __restrict__ W,
                                                   float* __restrict__ Cout,
                                                   int M, int N, int K) {
    __shared__ float As[64][17];
    __shared__ float Ws[64][17];
    int tx = threadIdx.x & 15, ty = threadIdx.x >> 4;
    int mbase = blockIdx.y * 64, nbase = blockIdx.x * 64;
    int lr = threadIdx.x >> 2, lk = (threadIdx.x & 3) * 4;
    float acc[4][4] = {};
    const float* Arow = A + (size_t)(mbase + lr) * K + lk;
    const float* Wrow = W + (size_t)(nbase + lr) * K + lk;
    for (int k0 = 0; k0 < K; k0 += 16) {
        float4 av = *(const float4*)(Arow + k0);
        float4 wv = *(const float4*)(Wrow + k0);
        As[lr][lk + 0] = av.x; As[lr][lk + 1] = av.y;
        As[lr][lk + 2] = av.z; As[lr][lk + 3] = av.w;
        Ws[lr][lk + 0] = wv.x; Ws[lr][lk + 1] = wv.y;
        Ws[lr][lk + 2] = wv.z; Ws[lr][lk + 3] = wv.w;
        __syncthreads();
#pragma unroll
        for (int kk = 0; kk < 16; ++kk) {
            float a0 = As[ty * 4 + 0][kk], a1 = As[ty * 4 + 1][kk];
            float a2 = As[ty * 4 + 2][kk], a3 = As[ty * 4 + 3][kk];
            float b0 = Ws[tx * 4 + 0][kk], b1 = Ws[tx * 4 + 1][kk];
            float b2 = Ws[tx * 4 + 2][kk], b3 = Ws[tx * 4 + 3][kk];
            acc[0][0] += a0 * b0; acc[0][1] += a0 * b1; acc[0][2] += a0 * b2; acc[0][3] += a0 * b3;
            acc[1][0] += a1 * b0; acc[1][1] += a1 * b1; acc[1][2] += a1 * b2; acc[1][3] += a1 * b3;
            acc[2][0] += a2 * b0; acc[2][1] += a2 * b1; acc[2][2] += a2 * b2; acc[2][3] += a2 * b3;
            acc[3][0] += a3 * b0; acc[3][1] += a3 * b1; acc[3][2] += a3 * b2; acc[3][3] += a3 * b3;
        }
        __syncthreads();
    }
#pragma unroll
    for (int i = 0; i < 4; ++i) {
        float4 o;
        float* po = &o.x;
#pragma unroll
        for (int j = 0; j < 4; ++j) {
            float vv = acc[i][j];
            if (EPI == 1) { vv = fmaxf(vv, 0.0f); vv = vv * vv; }
            po[j] = vv;
        }
        *(float4*)&Cout[(size_t)(mbase + ty * 4 + i) * N + nbase + tx * 4] = o;
    }
}

// ---------------- per-head RMS + RoPE (+ optional q_gain), in place ----------------
__global__ __launch_bounds__(256) void qknorm_kernel(float* __restrict__ q,
                                                     const float* __restrict__ cosT,
                                                     const float* __restrict__ sinT,
                                                     const float* __restrict__ gain) {
    int gid = blockIdx.x * blockDim.x + threadIdx.x;
    int gw = gid >> 6, lane = gid & 63;
    int head = gw & (HH - 1);
    int c = (gw >> 4) & (CC - 1);
    int b = gw >> 14;
    size_t off = ((size_t)(b * CC + c)) * DD + head * HDIM + lane;
    float v = q[off];
    float ss = v * v;
    for (int o = 32; o; o >>= 1) ss += __shfl_xor(ss, o);
    float r = rsqrtf(ss * (1.0f / HDIM) + F32_EPS);
    float vn = v * r;
    float other = __shfl_xor(vn, 32);
    int i = lane & 31;
    float cv = cosT[c * 32 + i], sv = sinT[c * 32 + i];
    float out = (lane < 32) ? (vn * cv + other * sv) : (vn * cv - other * sv);
    if (gain) out *= gain[head];
    q[off] = out;
}

// ---------------- causal flash attention (f32), one block per (b,h,qtile64) ----------------
__global__ __launch_bounds__(256) void attn_kernel(const float* __restrict__ q,
                                                   const float* __restrict__ k,
                                                   const float* __restrict__ v,
                                                   float* __restrict__ y) {
    __shared__ float Qs[64][65];
    __shared__ float Ks[64][65];   // reused as P after scores
    __shared__ float Vs[64][65];
    int blk = blockIdx.x;
    int qt = blk & 15, head = (blk >> 4) & (HH - 1), b = blk >> 8;
    int tx = threadIdx.x & 15, ty = threadIdx.x >> 4;
    int qbase = qt * 64;
    int lr = threadIdx.x >> 2, lc = (threadIdx.x & 3) * 16;

    {
        const float* src = &q[((size_t)(b * CC + qbase + lr)) * DD + head * HDIM + lc];
#pragma unroll
        for (int u = 0; u < 4; ++u) {
            float4 t4 = *(const float4*)(src + u * 4);
            Qs[lr][lc + u * 4 + 0] = t4.x; Qs[lr][lc + u * 4 + 1] = t4.y;
            Qs[lr][lc + u * 4 + 2] = t4.z; Qs[lr][lc + u * 4 + 3] = t4.w;
        }
    }
    float o[4][4] = {};
    float m[4] = {-INFINITY, -INFINITY, -INFINITY, -INFINITY};
    float lsum[4] = {};

    for (int kt = 0; kt <= qt; ++kt) {
        int kbase = kt * 64;
        __syncthreads();   // previous iteration's LDS reads done before overwrite
        {
            const float* kr = &k[((size_t)(b * CC + kbase + lr)) * DD + head * HDIM + lc];
            const float* vr = &v[((size_t)(b * CC + kbase + lr)) * DD + head * HDIM + lc];
#pragma unroll
            for (int u = 0; u < 4; ++u) {
                float4 kv4 = *(const float4*)(kr + u * 4);
                float4 vv4 = *(const float4*)(vr + u * 4);
                Ks[lr][lc + u * 4 + 0] = kv4.x; Ks[lr][lc + u * 4 + 1] = kv4.y;
                Ks[lr][lc + u * 4 + 2] = kv4.z; Ks[lr][lc + u * 4 + 3] = kv4.w;
                Vs[lr][lc + u * 4 + 0] = vv4.x; Vs[lr][lc + u * 4 + 1] = vv4.y;
                Vs[lr][lc + u * 4 + 2] = vv4.z; Vs[lr][lc + u * 4 + 3] = vv4.w;
            }
        }
        __syncthreads();

        float s[4][4] = {};
#pragma unroll 8
        for (int d = 0; d < 64; ++d) {
            float qa0 = Qs[ty * 4 + 0][d], qa1 = Qs[ty * 4 + 1][d];
            float qa2 = Qs[ty * 4 + 2][d], qa3 = Qs[ty * 4 + 3][d];
            float kb0 = Ks[tx * 4 + 0][d], kb1 = Ks[tx * 4 + 1][d];
            float kb2 = Ks[tx * 4 + 2][d], kb3 = Ks[tx * 4 + 3][d];
            s[0][0] += qa0 * kb0; s[0][1] += qa0 * kb1; s[0][2] += qa0 * kb2; s[0][3] += qa0 * kb3;
            s[1][0] += qa1 * kb0; s[1][1] += qa1 * kb1; s[1][2] += qa1 * kb2; s[1][3] += qa1 * kb3;
            s[2][0] += qa2 * kb0; s[2][1] += qa2 * kb1; s[2][2] += qa2 * kb2; s[2][3] += qa2 * kb3;
            s[3][0] += qa3 * kb0; s[3][1] += qa3 * kb1; s[3][2] += qa3 * kb2; s[3][3] += qa3 * kb3;
        }
#pragma unroll
        for (int i = 0; i < 4; ++i)
#pragma unroll
            for (int j = 0; j < 4; ++j) {
                s[i][j] *= 0.125f;   // 1/sqrt(64)
                if (kt == qt && (tx * 4 + j) > (ty * 4 + i)) s[i][j] = -INFINITY;
            }
        // online softmax per q-row (16 lanes per row, consecutive)
#pragma unroll
        for (int i = 0; i < 4; ++i) {
            float tmax = fmaxf(fmaxf(s[i][0], s[i][1]), fmaxf(s[i][2], s[i][3]));
            for (int off = 1; off < 16; off <<= 1) tmax = fmaxf(tmax, __shfl_xor(tmax, off));
            float mn = fmaxf(m[i], tmax);
            float alpha = expf(m[i] - mn);
            float p0 = expf(s[i][0] - mn), p1 = expf(s[i][1] - mn);
            float p2 = expf(s[i][2] - mn), p3 = expf(s[i][3] - mn);
            float tsum = p0 + p1 + p2 + p3;
            for (int off = 1; off < 16; off <<= 1) tsum += __shfl_xor(tsum, off);
            lsum[i] = lsum[i] * alpha + tsum;
#pragma unroll
            for (int j = 0; j < 4; ++j) o[i][j] *= alpha;
            m[i] = mn;
            s[i][0] = p0; s[i][1] = p1; s[i][2] = p2; s[i][3] = p3;
        }
        __syncthreads();   // scores reads of Ks done
#pragma unroll
        for (int i = 0; i < 4; ++i)
#pragma unroll
            for (int j = 0; j < 4; ++j) Ks[ty * 4 + i][tx * 4 + j] = s[i][j];
        __syncthreads();
#pragma unroll 8
        for (int kk = 0; kk < 64; ++kk) {
            float pa0 = Ks[ty * 4 + 0][kk], pa1 = Ks[ty * 4 + 1][kk];
            float pa2 = Ks[ty * 4 + 2][kk], pa3 = Ks[ty * 4 + 3][kk];
            float vb0 = Vs[kk][tx * 4 + 0], vb1 = Vs[kk][tx * 4 + 1];
            float vb2 = Vs[kk][tx * 4 + 2], vb3 = Vs[kk][tx * 4 + 3];
            o[0][0] += pa0 * vb0; o[0][1] += pa0 * vb1; o[0][2] += pa0 * vb2; o[0][3] += pa0 * vb3;
            o[1][0] += pa1 * vb0; o[1][1] += pa1 * vb1; o[1][2] += pa1 * vb2; o[1][3] += pa1 * vb3;
            o[2][0] += pa2 * vb0; o[2][1] += pa2 * vb1; o[2][2] += pa2 * vb2; o[2][3] += pa2 * vb3;
            o[3][0] += pa3 * vb0; o[3][1] += pa3 * vb1; o[3][2] += pa3 * vb2; o[3][3] += pa3 * vb3;
        }
    }
#pragma unroll
    for (int i = 0; i < 4; ++i) {
        float inv = 1.0f / lsum[i];
        float4 ov = make_float4(o[i][0] * inv, o[i][1] * inv, o[i][2] * inv, o[i][3] * inv);
        *(float4*)&y[((size_t)(b * CC + qbase + ty * 4 + i)) * DD + head * HDIM + tx * 4] = ov;
    }
}

// ---------------- h += scale (.) a ----------------
__global__ void resid_kernel(float* __restrict__ h, const float* __restrict__ a,
                             const float* __restrict__ scale) {
    int idx = blockIdx.x * blockDim.x + threadIdx.x;   // per float4
    size_t off = (size_t)idx * 4;
    float4 hv = *(float4*)&h[off];
    float4 av = *(const float4*)&a[off];
    float4 sv = *(const float4*)&scale[(idx & 255) * 4];
    hv.x += sv.x * av.x; hv.y += sv.y * av.y;
    hv.z += sv.z * av.z; hv.w += sv.w * av.w;
    *(float4*)&h[off] = hv;
}

// ---------------- out = h * valid ----------------
__global__ void mask_kernel(const float* __restrict__ h, const int* __restrict__ nch,
                            float* __restrict__ out) {
    int idx = blockIdx.x * blockDim.x + threadIdx.x;   // per float4
    int c = (idx >> 8) & (CC - 1);
    int b = idx >> 18;
    float4 hv = *(const float4*)&h[(size_t)idx * 4];
    if (c >= nch[b]) hv = make_float4(0.f, 0.f, 0.f, 0.f);
    *(float4*)&out[(size_t)idx * 4] = hv;
}

extern "C" void kernel_launch(void* const* d_in, const int* in_sizes, int n_in,
                              void* d_out, int out_size, void* d_ws, size_t ws_size,
                              hipStream_t stream) {
    const float* x        = (const float*)d_in[0];
    const int*   boundary = (const int*)d_in[1];
    const float* Wq       = (const float*)d_in[2];
    const float* Wk       = (const float*)d_in[3];
    const float* Wv       = (const float*)d_in[4];
    const float* Wo       = (const float*)d_in[5];
    const float* qg       = (const float*)d_in[6];
    const float* fcw      = (const float*)d_in[7];
    const float* projw    = (const float*)d_in[8];
    const float* ascale   = (const float*)d_in[9];
    const float* mscale   = (const float*)d_in[10];
    const float* rmix     = (const float*)d_in[11];
    float* out = (float*)d_out;

    const size_t NTOK = (size_t)BB * CC * DD;           // 4M floats
    const size_t HIDCHUNK = (size_t)1024 * DFF;         // MLP processed in 4 row-chunks

    float* ws   = (float*)d_ws;
    float* h    = ws;
    float* x0   = h + NTOK;
    float* xn   = x0 + NTOK;
    float* qb   = xn + NTOK;
    float* kb   = qb + NTOK;
    float* vb   = kb + NTOK;
    float* hid  = vb + NTOK;                            // 1024*4096 floats
    float* cosT = hid + HIDCHUNK;
    float* sinT = cosT + (size_t)CC * 32;
    int*   starts = (int*)(sinT + (size_t)CC * 32);     // BB*(CC+1)
    int*   nch    = starts + BB * (CC + 1);

    const int M = BB * CC;  // 4096 rows

    rope_init_kernel<<<CC * 32 / 256, 256, 0, stream>>>(cosT, sinT);
    scan_kernel<<<BB, 1024, 0, stream>>>(boundary, starts, nch);
    latents_kernel<<<dim3(CC, BB), 256, 0, stream>>>(x, starts, h, x0);

    for (int l = 0; l < LL; ++l) {
        // h = mix0*h + mix1*x0 ; xn = rms(h)
        rmsmix_kernel<<<M, 256, 0, stream>>>(h, x0, rmix + (size_t)l * 2 * DD, h, xn);
        // QKV
        gemm_kernel<0><<<dim3(DD / 64, M / 64), 256, 0, stream>>>(xn, Wq + (size_t)l * DD * DD, qb, M, DD, DD);
        gemm_kernel<0><<<dim3(DD / 64, M / 64), 256, 0, stream>>>(xn, Wk + (size_t)l * DD * DD, kb, M, DD, DD);
        gemm_kernel<0><<<dim3(DD / 64, M / 64), 256, 0, stream>>>(xn, Wv + (size_t)l * DD * DD, vb, M, DD, DD);
        // per-head RMS + RoPE (+gain for q)
        qknorm_kernel<<<(BB * CC * HH * 64) / 256, 256, 0, stream>>>(qb, cosT, sinT, qg + l * HH);
        qknorm_kernel<<<(BB * CC * HH * 64) / 256, 256, 0, stream>>>(kb, cosT, sinT, nullptr);
        // attention -> xn (free after QKV)
        attn_kernel<<<BB * HH * 16, 256, 0, stream>>>(qb, kb, vb, xn);
        // a = y @ Wo^T -> qb (free)
        gemm_kernel<0><<<dim3(DD / 64, M / 64), 256, 0, stream>>>(xn, Wo + (size_t)l * DD * DD, qb, M, DD, DD);
        resid_kernel<<<(int)(NTOK / 4 / 256), 256, 0, stream>>>(h, qb, ascale + l * DD);
        // MLP: xn = rms(h); hid = relu(xn@fc^T)^2 (row-chunked); a = hid@proj^T -> qb
        rmsmix_kernel<<<M, 256, 0, stream>>>(h, nullptr, nullptr, nullptr, xn);
        for (int r0 = 0; r0 < M; r0 += 1024) {
            gemm_kernel<1><<<dim3(DFF / 64, 1024 / 64), 256, 0, stream>>>(
                xn + (size_t)r0 * DD, fcw + (size_t)l * DFF * DD, hid, 1024, DFF, DD);
            gemm_kernel<0><<<dim3(DD / 64, 1024 / 64), 256, 0, stream>>>(
                hid, projw + (size_t)l * DD * DFF, qb + (size_t)r0 * DD, 1024, DD, DFF);
        }
        resid_kernel<<<(int)(NTOK / 4 / 256), 256, 0, stream>>>(h, qb, mscale + l * DD);
    }
    mask_kernel<<<(int)(NTOK / 4 / 256), 256, 0, stream>>>(h, nch, out);
}

// Round 2
// 3893.442 us; speedup vs baseline: 3.0147x; 3.0147x over previous
//
#include <hip/hip_runtime.h>
#include <math.h>

// Problem constants (fixed by reference)
#define BB   4
#define SS   4096
#define DD   1024
#define HH   16
#define HDIM 64
#define CC   1024      // MAX_CHUNKS
#define DFF  4096
#define LL   4

static constexpr float F32_EPS = 1.1920928955078125e-07f;  // jnp.finfo(f32).eps

typedef __attribute__((ext_vector_type(8))) __bf16 bf16x8;
typedef __attribute__((ext_vector_type(4))) float  f32x4;

__device__ __forceinline__ uint f2bf(float f) {
    uint u = __float_as_uint(f);
    return (u + 0x7fffu + ((u >> 16) & 1u)) >> 16;   // RNE
}

// ---------------- f32 -> bf16 cast (8 elems/thread) ----------------
__global__ __launch_bounds__(256) void cast_kernel(const float* __restrict__ in,
                                                   ushort* __restrict__ out, int n8) {
    int i = blockIdx.x * blockDim.x + threadIdx.x;
    if (i >= n8) return;
    const float4* p = (const float4*)(in + (size_t)i * 8);
    float4 a = p[0], b = p[1];
    uint4 o;
    o.x = f2bf(a.x) | (f2bf(a.y) << 16);
    o.y = f2bf(a.z) | (f2bf(a.w) << 16);
    o.z = f2bf(b.x) | (f2bf(b.y) << 16);
    o.w = f2bf(b.z) | (f2bf(b.w) << 16);
    *(uint4*)(out + (size_t)i * 8) = o;
}

// ---------------- RoPE tables ----------------
__global__ void rope_init_kernel(float* __restrict__ cosT, float* __restrict__ sinT) {
    int idx = blockIdx.x * blockDim.x + threadIdx.x;   // over CC*32
    int pos = idx >> 5;
    int i   = idx & 31;
    float inv = powf(10000.0f, -(float)i / 32.0f);
    float f = (float)pos * inv;
    cosT[idx] = cosf(f);
    sinT[idx] = sinf(f);
}

// ---------------- boundary scan -> chunk starts, num_chunks ----------------
__global__ __launch_bounds__(1024) void scan_kernel(const int* __restrict__ boundary,
                                                    int* __restrict__ starts,
                                                    int* __restrict__ nch) {
    __shared__ int tmp[1024];
    int b = blockIdx.x, t = threadIdx.x;
    int base = b * SS + t * 4;
    int v0 = boundary[base + 0], v1 = boundary[base + 1];
    int v2 = boundary[base + 2], v3 = boundary[base + 3];
    int p0 = v0, p1 = p0 + v1, p2 = p1 + v2, p3 = p2 + v3;
    tmp[t] = p3;
    __syncthreads();
    for (int off = 1; off < 1024; off <<= 1) {
        int add = (t >= off) ? tmp[t - off] : 0;
        __syncthreads();
        tmp[t] += add;
        __syncthreads();
    }
    int excl = tmp[t] - p3;
    if (v0) starts[b * (CC + 1) + (excl + p0 - 1)] = t * 4 + 0;
    if (v1) starts[b * (CC + 1) + (excl + p1 - 1)] = t * 4 + 1;
    if (v2) starts[b * (CC + 1) + (excl + p2 - 1)] = t * 4 + 2;
    if (v3) starts[b * (CC + 1) + (excl + p3 - 1)] = t * 4 + 3;
    int total = tmp[1023];
    if (t == 0) nch[b] = total;
    for (int c = t; c <= CC; c += 1024)
        if (c >= total) starts[b * (CC + 1) + c] = SS;
}

// ---------------- chunk means -> h and x0 ----------------
__global__ __launch_bounds__(256) void latents_kernel(const float* __restrict__ x,
                                                      const int* __restrict__ starts,
                                                      float* __restrict__ h,
                                                      float* __restrict__ x0) {
    int c = blockIdx.x, b = blockIdx.y, t = threadIdx.x;
    int s0 = starts[b * (CC + 1) + c];
    int s1 = starts[b * (CC + 1) + c + 1];
    float a0 = 0.f, a1 = 0.f, a2 = 0.f, a3 = 0.f;
    for (int r = s0; r < s1; ++r) {
        const float4 xv = *(const float4*)&x[((size_t)(b * SS + r)) * DD + t * 4];
        a0 += xv.x; a1 += xv.y; a2 += xv.z; a3 += xv.w;
    }
    float inv = (s1 > s0) ? 1.0f / (float)(s1 - s0) : 0.0f;
    float4 o = make_float4(a0 * inv, a1 * inv, a2 * inv, a3 * inv);
    size_t off = ((size_t)(b * CC + c)) * DD + t * 4;
    *(float4*)&h[off]  = o;
    *(float4*)&x0[off] = o;
}

// ---------------- optional resid-mix + row RMS norm, bf16 normed output ----------------
__global__ __launch_bounds__(256) void rmsmix_kernel(const float* __restrict__ hin,
                                                     const float* __restrict__ x0,
                                                     const float* __restrict__ mix,
                                                     float* __restrict__ hout,
                                                     ushort* __restrict__ xnout) {
    int row = blockIdx.x, t = threadIdx.x;
    size_t off = (size_t)row * DD + t * 4;
    float4 hv = *(const float4*)&hin[off];
    if (mix) {
        float4 m0 = *(const float4*)&mix[t * 4];
        float4 m1 = *(const float4*)&mix[DD + t * 4];
        float4 xv = *(const float4*)&x0[off];
        hv.x = m0.x * hv.x + m1.x * xv.x;
        hv.y = m0.y * hv.y + m1.y * xv.y;
        hv.z = m0.z * hv.z + m1.z * xv.z;
        hv.w = m0.w * hv.w + m1.w * xv.w;
    }
    float ss = hv.x * hv.x + hv.y * hv.y + hv.z * hv.z + hv.w * hv.w;
    for (int o = 32; o; o >>= 1) ss += __shfl_xor(ss, o);
    __shared__ float wsum[4];
    int lane = t & 63, wid = t >> 6;
    if (lane == 0) wsum[wid] = ss;
    __syncthreads();
    float tot = wsum[0] + wsum[1] + wsum[2] + wsum[3];
    float r = rsqrtf(tot * (1.0f / DD) + F32_EPS);
    if (hout) *(float4*)&hout[off] = hv;
    uint2 pk;
    pk.x = f2bf(hv.x * r) | (f2bf(hv.y * r) << 16);
    pk.y = f2bf(hv.z * r) | (f2bf(hv.w * r) << 16);
    *(uint2*)&xnout[off] = pk;
}

// ---------------- bf16 MFMA GEMM: C[M,N] = A[M,K] @ W[N,K]^T ----------------
// 128x128 tile, BK=64, 256 threads (4 waves, 2x2 quadrants), reg-staged LDS with
// T2 XOR swizzle on both write & read (conflict-free ds_read_b128).
// EPI 0: f32 store; EPI 1: relu(x)^2, bf16 store.
template <int EPI>
__global__ __launch_bounds__(256) void gemm_bf16(const ushort* __restrict__ A,
                                                 const ushort* __restrict__ W,
                                                 float* __restrict__ Cf,
                                                 ushort* __restrict__ Cb,
                                                 int M, int N, int K) {
    __shared__ __align__(16) ushort Als[128 * 64];
    __shared__ __align__(16) ushort Wls[128 * 64];
    const int tid  = threadIdx.x;
    const int wid  = tid >> 6, lane = tid & 63;
    const int wr   = wid >> 1, wc   = wid & 1;
    const int l15  = lane & 15, lhi = lane >> 4;
    const int mbase = blockIdx.y * 128, nbase = blockIdx.x * 128;

    f32x4 acc[4][4] = {};

    // staging: thread covers rows (tid>>3)+s*32, 16B chunk (tid&7) within row
    const int srow = tid >> 3;
    const int scol = (tid & 7) * 8;                       // element col of 16B chunk
    const int ssw  = scol ^ (((tid >> 3) & 7) << 3);      // swizzled element col
    const ushort* Agp = A + (size_t)(mbase + srow) * K + scol;
    const ushort* Wgp = W + (size_t)(nbase + srow) * K + scol;
    ushort* Adst = &Als[srow * 64 + ssw];
    ushort* Wdst = &Wls[srow * 64 + ssw];

    int4 avr[4], wvr[4];
#pragma unroll
    for (int s = 0; s < 4; ++s) {
        avr[s] = *(const int4*)(Agp + (size_t)s * 32 * K);
        wvr[s] = *(const int4*)(Wgp + (size_t)s * 32 * K);
    }

    const int swz = (l15 & 7) << 3;
    const ushort* Afr = &Als[(wr * 64 + l15) * 64];
    const ushort* Wfr = &Wls[(wc * 64 + l15) * 64];

    for (int k0 = 0; k0 < K; k0 += 64) {
        __syncthreads();
#pragma unroll
        for (int s = 0; s < 4; ++s) {
            *(int4*)(Adst + s * 2048) = avr[s];
            *(int4*)(Wdst + s * 2048) = wvr[s];
        }
        __syncthreads();
        if (k0 + 64 < K) {
#pragma unroll
            for (int s = 0; s < 4; ++s) {
                avr[s] = *(const int4*)(Agp + k0 + 64 + (size_t)s * 32 * K);
                wvr[s] = *(const int4*)(Wgp + k0 + 64 + (size_t)s * 32 * K);
            }
        }
#pragma unroll
        for (int ks = 0; ks < 2; ++ks) {
            const int fcol = (ks * 32 + lhi * 8) ^ swz;
            bf16x8 af[4], bfm[4];
#pragma unroll
            for (int m = 0; m < 4; ++m)
                af[m] = *(const bf16x8*)(Afr + m * 1024 + fcol);
#pragma unroll
            for (int n = 0; n < 4; ++n)
                bfm[n] = *(const bf16x8*)(Wfr + n * 1024 + fcol);
#pragma unroll
            for (int m = 0; m < 4; ++m)
#pragma unroll
                for (int n = 0; n < 4; ++n)
                    acc[m][n] = __builtin_amdgcn_mfma_f32_16x16x32_bf16(
                        af[m], bfm[n], acc[m][n], 0, 0, 0);
        }
    }

    const int row0 = mbase + wr * 64 + lhi * 4;
    const int col0 = nbase + wc * 64 + l15;
#pragma unroll
    for (int m = 0; m < 4; ++m)
#pragma unroll
        for (int n = 0; n < 4; ++n) {
            int cc = col0 + n * 16;
#pragma unroll
            for (int r = 0; r < 4; ++r) {
                int rr = row0 + m * 16 + r;
                float v = acc[m][n][r];
                if (EPI == 1) {
                    v = fmaxf(v, 0.0f); v = v * v;
                    Cb[(size_t)rr * N + cc] = (ushort)f2bf(v);
                } else {
                    Cf[(size_t)rr * N + cc] = v;
                }
            }
        }
}

// ---------------- per-head RMS + RoPE (+ optional q_gain), f32 in place ----------------
__global__ __launch_bounds__(256) void qknorm_kernel(float* __restrict__ q,
                                                     const float* __restrict__ cosT,
                                                     const float* __restrict__ sinT,
                                                     const float* __restrict__ gain) {
    int gid = blockIdx.x * blockDim.x + threadIdx.x;
    int gw = gid >> 6, lane = gid & 63;
    int head = gw & (HH - 1);
    int c = (gw >> 4) & (CC - 1);
    int b = gw >> 14;
    size_t off = ((size_t)(b * CC + c)) * DD + head * HDIM + lane;
    float v = q[off];
    float ss = v * v;
    for (int o = 32; o; o >>= 1) ss += __shfl_xor(ss, o);
    float r = rsqrtf(ss * (1.0f / HDIM) + F32_EPS);
    float vn = v * r;
    float other = __shfl_xor(vn, 32);
    int i = lane & 31;
    float cv = cosT[c * 32 + i], sv = sinT[c * 32 + i];
    float out = (lane < 32) ? (vn * cv + other * sv) : (vn * cv - other * sv);
    if (gain) out *= gain[head];
    q[off] = out;
}

// ---------------- causal flash attention (f32 compute, bf16 output) ----------------
__global__ __launch_bounds__(256) void attn_kernel(const float* __restrict__ q,
                                                   const float* __restrict__ k,
                                                   const float* __restrict__ v,
                                                   ushort* __restrict__ y) {
    __shared__ float Qs[64][65];
    __shared__ float Ks[64][65];   // reused as P after scores
    __shared__ float Vs[64][65];
    int blk = blockIdx.x;
    int qt = blk & 15, head = (blk >> 4) & (HH - 1), b = blk >> 8;
    int tx = threadIdx.x & 15, ty = threadIdx.x >> 4;
    int qbase = qt * 64;
    int lr = threadIdx.x >> 2, lc = (threadIdx.x & 3) * 16;

    {
        const float* src = &q[((size_t)(b * CC + qbase + lr)) * DD + head * HDIM + lc];
#pragma unroll
        for (int u = 0; u < 4; ++u) {
            float4 t4 = *(const float4*)(src + u * 4);
            Qs[lr][lc + u * 4 + 0] = t4.x; Qs[lr][lc + u * 4 + 1] = t4.y;
            Qs[lr][lc + u * 4 + 2] = t4.z; Qs[lr][lc + u * 4 + 3] = t4.w;
        }
    }
    float o[4][4] = {};
    float m[4] = {-INFINITY, -INFINITY, -INFINITY, -INFINITY};
    float lsum[4] = {};

    for (int kt = 0; kt <= qt; ++kt) {
        int kbase = kt * 64;
        __syncthreads();
        {
            const float* kr = &k[((size_t)(b * CC + kbase + lr)) * DD + head * HDIM + lc];
            const float* vr = &v[((size_t)(b * CC + kbase + lr)) * DD + head * HDIM + lc];
#pragma unroll
            for (int u = 0; u < 4; ++u) {
                float4 kv4 = *(const float4*)(kr + u * 4);
                float4 vv4 = *(const float4*)(vr + u * 4);
                Ks[lr][lc + u * 4 + 0] = kv4.x; Ks[lr][lc + u * 4 + 1] = kv4.y;
                Ks[lr][lc + u * 4 + 2] = kv4.z; Ks[lr][lc + u * 4 + 3] = kv4.w;
                Vs[lr][lc + u * 4 + 0] = vv4.x; Vs[lr][lc + u * 4 + 1] = vv4.y;
                Vs[lr][lc + u * 4 + 2] = vv4.z; Vs[lr][lc + u * 4 + 3] = vv4.w;
            }
        }
        __syncthreads();

        float s[4][4] = {};
#pragma unroll 8
        for (int d = 0; d < 64; ++d) {
            float qa0 = Qs[ty * 4 + 0][d], qa1 = Qs[ty * 4 + 1][d];
            float qa2 = Qs[ty * 4 + 2][d], qa3 = Qs[ty * 4 + 3][d];
            float kb0 = Ks[tx * 4 + 0][d], kb1 = Ks[tx * 4 + 1][d];
            float kb2 = Ks[tx * 4 + 2][d], kb3 = Ks[tx * 4 + 3][d];
            s[0][0] += qa0 * kb0; s[0][1] += qa0 * kb1; s[0][2] += qa0 * kb2; s[0][3] += qa0 * kb3;
            s[1][0] += qa1 * kb0; s[1][1] += qa1 * kb1; s[1][2] += qa1 * kb2; s[1][3] += qa1 * kb3;
            s[2][0] += qa2 * kb0; s[2][1] += qa2 * kb1; s[2][2] += qa2 * kb2; s[2][3] += qa2 * kb3;
            s[3][0] += qa3 * kb0; s[3][1] += qa3 * kb1; s[3][2] += qa3 * kb2; s[3][3] += qa3 * kb3;
        }
#pragma unroll
        for (int i = 0; i < 4; ++i)
#pragma unroll
            for (int j = 0; j < 4; ++j) {
                s[i][j] *= 0.125f;   // 1/sqrt(64)
                if (kt == qt && (tx * 4 + j) > (ty * 4 + i)) s[i][j] = -INFINITY;
            }
#pragma unroll
        for (int i = 0; i < 4; ++i) {
            float tmax = fmaxf(fmaxf(s[i][0], s[i][1]), fmaxf(s[i][2], s[i][3]));
            for (int off = 1; off < 16; off <<= 1) tmax = fmaxf(tmax, __shfl_xor(tmax, off));
            float mn = fmaxf(m[i], tmax);
            float alpha = expf(m[i] - mn);
            float p0 = expf(s[i][0] - mn), p1 = expf(s[i][1] - mn);
            float p2 = expf(s[i][2] - mn), p3 = expf(s[i][3] - mn);
            float tsum = p0 + p1 + p2 + p3;
            for (int off = 1; off < 16; off <<= 1) tsum += __shfl_xor(tsum, off);
            lsum[i] = lsum[i] * alpha + tsum;
#pragma unroll
            for (int j = 0; j < 4; ++j) o[i][j] *= alpha;
            m[i] = mn;
            s[i][0] = p0; s[i][1] = p1; s[i][2] = p2; s[i][3] = p3;
        }
        __syncthreads();
#pragma unroll
        for (int i = 0; i < 4; ++i)
#pragma unroll
            for (int j = 0; j < 4; ++j) Ks[ty * 4 + i][tx * 4 + j] = s[i][j];
        __syncthreads();
#pragma unroll 8
        for (int kk = 0; kk < 64; ++kk) {
            float pa0 = Ks[ty * 4 + 0][kk], pa1 = Ks[ty * 4 + 1][kk];
            float pa2 = Ks[ty * 4 + 2][kk], pa3 = Ks[ty * 4 + 3][kk];
            float vb0 = Vs[kk][tx * 4 + 0], vb1 = Vs[kk][tx * 4 + 1];
            float vb2 = Vs[kk][tx * 4 + 2], vb3 = Vs[kk][tx * 4 + 3];
            o[0][0] += pa0 * vb0; o[0][1] += pa0 * vb1; o[0][2] += pa0 * vb2; o[0][3] += pa0 * vb3;
            o[1][0] += pa1 * vb0; o[1][1] += pa1 * vb1; o[1][2] += pa1 * vb2; o[1][3] += pa1 * vb3;
            o[2][0] += pa2 * vb0; o[2][1] += pa2 * vb1; o[2][2] += pa2 * vb2; o[2][3] += pa2 * vb3;
            o[3][0] += pa3 * vb0; o[3][1] += pa3 * vb1; o[3][2] += pa3 * vb2; o[3][3] += pa3 * vb3;
        }
    }
#pragma unroll
    for (int i = 0; i < 4; ++i) {
        float inv = 1.0f / lsum[i];
        uint2 pk;
        pk.x = f2bf(o[i][0] * inv) | (f2bf(o[i][1] * inv) << 16);
        pk.y = f2bf(o[i][2] * inv) | (f2bf(o[i][3] * inv) << 16);
        *(uint2*)&y[((size_t)(b * CC + qbase + ty * 4 + i)) * DD + head * HDIM + tx * 4] = pk;
    }
}

// ---------------- h += scale (.) a ----------------
__global__ void resid_kernel(float* __restrict__ h, const float* __restrict__ a,
                             const float* __restrict__ scale) {
    int idx = blockIdx.x * blockDim.x + threadIdx.x;   // per float4
    size_t off = (size_t)idx * 4;
    float4 hv = *(float4*)&h[off];
    float4 av = *(const float4*)&a[off];
    float4 sv = *(const float4*)&scale[(idx & 255) * 4];
    hv.x += sv.x * av.x; hv.y += sv.y * av.y;
    hv.z += sv.z * av.z; hv.w += sv.w * av.w;
    *(float4*)&h[off] = hv;
}

// ---------------- out = h * valid ----------------
__global__ void mask_kernel(const float* __restrict__ h, const int* __restrict__ nch,
                            float* __restrict__ out) {
    int idx = blockIdx.x * blockDim.x + threadIdx.x;   // per float4
    int c = (idx >> 8) & (CC - 1);
    int b = idx >> 18;
    float4 hv = *(const float4*)&h[(size_t)idx * 4];
    if (c >= nch[b]) hv = make_float4(0.f, 0.f, 0.f, 0.f);
    *(float4*)&out[(size_t)idx * 4] = hv;
}

extern "C" void kernel_launch(void* const* d_in, const int* in_sizes, int n_in,
                              void* d_out, int out_size, void* d_ws, size_t ws_size,
                              hipStream_t stream) {
    const float* x        = (const float*)d_in[0];
    const int*   boundary = (const int*)d_in[1];
    const float* Wq       = (const float*)d_in[2];
    const float* Wk       = (const float*)d_in[3];
    const float* Wv       = (const float*)d_in[4];
    const float* Wo       = (const float*)d_in[5];
    const float* qg       = (const float*)d_in[6];
    const float* fcw      = (const float*)d_in[7];
    const float* projw    = (const float*)d_in[8];
    const float* ascale   = (const float*)d_in[9];
    const float* mscale   = (const float*)d_in[10];
    const float* rmix     = (const float*)d_in[11];
    float* out = (float*)d_out;

    const size_t NTOK = (size_t)BB * CC * DD;           // 4M elems
    const size_t NHID = (size_t)BB * CC * DFF;          // 16M elems

    float* ws   = (float*)d_ws;
    float*  h    = ws;
    float*  x0   = h  + NTOK;
    float*  qb   = x0 + NTOK;
    float*  kb   = qb + NTOK;
    float*  vb   = kb + NTOK;
    ushort* xnb  = (ushort*)(vb + NTOK);
    ushort* ybf  = xnb + NTOK;
    ushort* hidb = ybf + NTOK;           // 16M bf16
    ushort* wbuf = hidb + NHID;          // 16M bf16 (reused for every weight matrix)
    float*  cosT = (float*)(wbuf + NHID);
    float*  sinT = cosT + (size_t)CC * 32;
    int*    starts = (int*)(sinT + (size_t)CC * 32);
    int*    nch    = starts + BB * (CC + 1);

    const int M = BB * CC;  // 4096 rows
    const int CAST_D2  = (int)(DD * DD / 8 / 256);      // blocks for D*D cast
    const int CAST_DF  = (int)(DD * DFF / 8 / 256);     // blocks for D*DFF cast

    rope_init_kernel<<<CC * 32 / 256, 256, 0, stream>>>(cosT, sinT);
    scan_kernel<<<BB, 1024, 0, stream>>>(boundary, starts, nch);
    latents_kernel<<<dim3(CC, BB), 256, 0, stream>>>(x, starts, h, x0);

    for (int l = 0; l < LL; ++l) {
        // h = mix0*h + mix1*x0 ; xnb = bf16(rms(h))
        rmsmix_kernel<<<M, 256, 0, stream>>>(h, x0, rmix + (size_t)l * 2 * DD, h, xnb);
        // QKV (bf16 MFMA; weights cast on demand into wbuf)
        cast_kernel<<<CAST_D2, 256, 0, stream>>>(Wq + (size_t)l * DD * DD, wbuf, DD * DD / 8);
        gemm_bf16<0><<<dim3(DD / 128, M / 128), 256, 0, stream>>>(xnb, wbuf, qb, nullptr, M, DD, DD);
        cast_kernel<<<CAST_D2, 256, 0, stream>>>(Wk + (size_t)l * DD * DD, wbuf, DD * DD / 8);
        gemm_bf16<0><<<dim3(DD / 128, M / 128), 256, 0, stream>>>(xnb, wbuf, kb, nullptr, M, DD, DD);
        cast_kernel<<<CAST_D2, 256, 0, stream>>>(Wv + (size_t)l * DD * DD, wbuf, DD * DD / 8);
        gemm_bf16<0><<<dim3(DD / 128, M / 128), 256, 0, stream>>>(xnb, wbuf, vb, nullptr, M, DD, DD);
        // per-head RMS + RoPE (+gain for q), f32 in place
        qknorm_kernel<<<(BB * CC * HH * 64) / 256, 256, 0, stream>>>(qb, cosT, sinT, qg + l * HH);
        qknorm_kernel<<<(BB * CC * HH * 64) / 256, 256, 0, stream>>>(kb, cosT, sinT, nullptr);
        // attention -> ybf (bf16)
        attn_kernel<<<BB * HH * 16, 256, 0, stream>>>(qb, kb, vb, ybf);
        // a = y @ Wo^T -> qb (f32)
        cast_kernel<<<CAST_D2, 256, 0, stream>>>(Wo + (size_t)l * DD * DD, wbuf, DD * DD / 8);
        gemm_bf16<0><<<dim3(DD / 128, M / 128), 256, 0, stream>>>(ybf, wbuf, qb, nullptr, M, DD, DD);
        resid_kernel<<<(int)(NTOK / 4 / 256), 256, 0, stream>>>(h, qb, ascale + l * DD);
        // MLP
        rmsmix_kernel<<<M, 256, 0, stream>>>(h, nullptr, nullptr, nullptr, xnb);
        cast_kernel<<<CAST_DF, 256, 0, stream>>>(fcw + (size_t)l * DFF * DD, wbuf, DD * DFF / 8);
        gemm_bf16<1><<<dim3(DFF / 128, M / 128), 256, 0, stream>>>(xnb, wbuf, nullptr, hidb, M, DFF, DD);
        cast_kernel<<<CAST_DF, 256, 0, stream>>>(projw + (size_t)l * DD * DFF, wbuf, DD * DFF / 8);
        gemm_bf16<0><<<dim3(DD / 128, M / 128), 256, 0, stream>>>(hidb, wbuf, qb, nullptr, M, DD, DFF);
        resid_kernel<<<(int)(NTOK / 4 / 256), 256, 0, stream>>>(h, qb, mscale + l * DD);
    }
    mask_kernel<<<(int)(NTOK / 4 / 256), 256, 0, stream>>>(h, nch, out);
}

// Round 3
// 2665.188 us; speedup vs baseline: 4.4040x; 1.4609x over previous
//
#include <hip/hip_runtime.h>
#include <math.h>

// Problem constants (fixed by reference)
#define BB   4
#define SS   4096
#define DD   1024
#define HH   16
#define HDIM 64
#define CC   1024      // MAX_CHUNKS
#define DFF  4096
#define LL   4

static constexpr float F32_EPS = 1.1920928955078125e-07f;  // jnp.finfo(f32).eps

typedef __attribute__((ext_vector_type(8))) __bf16 bf16x8;
typedef __attribute__((ext_vector_type(4))) float  f32x4;

__device__ __forceinline__ uint f2bf(float f) {
    uint u = __float_as_uint(f);
    return (u + 0x7fffu + ((u >> 16) & 1u)) >> 16;   // RNE
}

// ---------------- f32 -> bf16 cast (8 elems/thread) ----------------
__global__ __launch_bounds__(256) void cast_kernel(const float* __restrict__ in,
                                                   ushort* __restrict__ out, int n8) {
    int i = blockIdx.x * blockDim.x + threadIdx.x;
    if (i >= n8) return;
    const float4* p = (const float4*)(in + (size_t)i * 8);
    float4 a = p[0], b = p[1];
    uint4 o;
    o.x = f2bf(a.x) | (f2bf(a.y) << 16);
    o.y = f2bf(a.z) | (f2bf(a.w) << 16);
    o.z = f2bf(b.x) | (f2bf(b.y) << 16);
    o.w = f2bf(b.z) | (f2bf(b.w) << 16);
    *(uint4*)(out + (size_t)i * 8) = o;
}

// ---------------- RoPE tables ----------------
__global__ void rope_init_kernel(float* __restrict__ cosT, float* __restrict__ sinT) {
    int idx = blockIdx.x * blockDim.x + threadIdx.x;   // over CC*32
    int pos = idx >> 5;
    int i   = idx & 31;
    float inv = powf(10000.0f, -(float)i / 32.0f);
    float f = (float)pos * inv;
    cosT[idx] = cosf(f);
    sinT[idx] = sinf(f);
}

// ---------------- boundary scan -> chunk starts, num_chunks ----------------
__global__ __launch_bounds__(1024) void scan_kernel(const int* __restrict__ boundary,
                                                    int* __restrict__ starts,
                                                    int* __restrict__ nch) {
    __shared__ int tmp[1024];
    int b = blockIdx.x, t = threadIdx.x;
    int base = b * SS + t * 4;
    int v0 = boundary[base + 0], v1 = boundary[base + 1];
    int v2 = boundary[base + 2], v3 = boundary[base + 3];
    int p0 = v0, p1 = p0 + v1, p2 = p1 + v2, p3 = p2 + v3;
    tmp[t] = p3;
    __syncthreads();
    for (int off = 1; off < 1024; off <<= 1) {
        int add = (t >= off) ? tmp[t - off] : 0;
        __syncthreads();
        tmp[t] += add;
        __syncthreads();
    }
    int excl = tmp[t] - p3;
    if (v0) starts[b * (CC + 1) + (excl + p0 - 1)] = t * 4 + 0;
    if (v1) starts[b * (CC + 1) + (excl + p1 - 1)] = t * 4 + 1;
    if (v2) starts[b * (CC + 1) + (excl + p2 - 1)] = t * 4 + 2;
    if (v3) starts[b * (CC + 1) + (excl + p3 - 1)] = t * 4 + 3;
    int total = tmp[1023];
    if (t == 0) nch[b] = total;
    for (int c = t; c <= CC; c += 1024)
        if (c >= total) starts[b * (CC + 1) + c] = SS;
}

// ---------------- chunk means -> h and x0 ----------------
__global__ __launch_bounds__(256) void latents_kernel(const float* __restrict__ x,
                                                      const int* __restrict__ starts,
                                                      float* __restrict__ h,
                                                      float* __restrict__ x0) {
    int c = blockIdx.x, b = blockIdx.y, t = threadIdx.x;
    int s0 = starts[b * (CC + 1) + c];
    int s1 = starts[b * (CC + 1) + c + 1];
    float a0 = 0.f, a1 = 0.f, a2 = 0.f, a3 = 0.f;
    for (int r = s0; r < s1; ++r) {
        const float4 xv = *(const float4*)&x[((size_t)(b * SS + r)) * DD + t * 4];
        a0 += xv.x; a1 += xv.y; a2 += xv.z; a3 += xv.w;
    }
    float inv = (s1 > s0) ? 1.0f / (float)(s1 - s0) : 0.0f;
    float4 o = make_float4(a0 * inv, a1 * inv, a2 * inv, a3 * inv);
    size_t off = ((size_t)(b * CC + c)) * DD + t * 4;
    *(float4*)&h[off]  = o;
    *(float4*)&x0[off] = o;
}

// ---------------- optional resid-mix + row RMS norm, bf16 normed output ----------------
__global__ __launch_bounds__(256) void rmsmix_kernel(const float* __restrict__ hin,
                                                     const float* __restrict__ x0,
                                                     const float* __restrict__ mix,
                                                     float* __restrict__ hout,
                                                     ushort* __restrict__ xnout) {
    int row = blockIdx.x, t = threadIdx.x;
    size_t off = (size_t)row * DD + t * 4;
    float4 hv = *(const float4*)&hin[off];
    if (mix) {
        float4 m0 = *(const float4*)&mix[t * 4];
        float4 m1 = *(const float4*)&mix[DD + t * 4];
        float4 xv = *(const float4*)&x0[off];
        hv.x = m0.x * hv.x + m1.x * xv.x;
        hv.y = m0.y * hv.y + m1.y * xv.y;
        hv.z = m0.z * hv.z + m1.z * xv.z;
        hv.w = m0.w * hv.w + m1.w * xv.w;
    }
    float ss = hv.x * hv.x + hv.y * hv.y + hv.z * hv.z + hv.w * hv.w;
    for (int o = 32; o; o >>= 1) ss += __shfl_xor(ss, o);
    __shared__ float wsum[4];
    int lane = t & 63, wid = t >> 6;
    if (lane == 0) wsum[wid] = ss;
    __syncthreads();
    float tot = wsum[0] + wsum[1] + wsum[2] + wsum[3];
    float r = rsqrtf(tot * (1.0f / DD) + F32_EPS);
    if (hout) *(float4*)&hout[off] = hv;
    uint2 pk;
    pk.x = f2bf(hv.x * r) | (f2bf(hv.y * r) << 16);
    pk.y = f2bf(hv.z * r) | (f2bf(hv.w * r) << 16);
    *(uint2*)&xnout[off] = pk;
}

// ---------------- bf16 MFMA GEMM: C[M,N] = A[M,K] @ W[N,K]^T ----------------
// 128x128 tile, BK=64, 256 threads (4 waves, 2x2 quadrants), reg-staged LDS with
// T2 XOR swizzle on both write & read (conflict-free ds_read_b128).
// EPI 0: f32 store; EPI 1: relu(x)^2 bf16 store; EPI 2: plain bf16 store.
template <int EPI>
__global__ __launch_bounds__(256) void gemm_bf16(const ushort* __restrict__ A,
                                                 const ushort* __restrict__ W,
                                                 float* __restrict__ Cf,
                                                 ushort* __restrict__ Cb,
                                                 int M, int N, int K) {
    __shared__ __align__(16) ushort Als[128 * 64];
    __shared__ __align__(16) ushort Wls[128 * 64];
    const int tid  = threadIdx.x;
    const int wid  = tid >> 6, lane = tid & 63;
    const int wr   = wid >> 1, wc   = wid & 1;
    const int l15  = lane & 15, lhi = lane >> 4;
    const int mbase = blockIdx.y * 128, nbase = blockIdx.x * 128;

    f32x4 acc[4][4] = {};

    const int srow = tid >> 3;
    const int scol = (tid & 7) * 8;
    const int ssw  = scol ^ (((tid >> 3) & 7) << 3);
    const ushort* Agp = A + (size_t)(mbase + srow) * K + scol;
    const ushort* Wgp = W + (size_t)(nbase + srow) * K + scol;
    ushort* Adst = &Als[srow * 64 + ssw];
    ushort* Wdst = &Wls[srow * 64 + ssw];

    int4 avr[4], wvr[4];
#pragma unroll
    for (int s = 0; s < 4; ++s) {
        avr[s] = *(const int4*)(Agp + (size_t)s * 32 * K);
        wvr[s] = *(const int4*)(Wgp + (size_t)s * 32 * K);
    }

    const int swz = (l15 & 7) << 3;
    const ushort* Afr = &Als[(wr * 64 + l15) * 64];
    const ushort* Wfr = &Wls[(wc * 64 + l15) * 64];

    for (int k0 = 0; k0 < K; k0 += 64) {
        __syncthreads();
#pragma unroll
        for (int s = 0; s < 4; ++s) {
            *(int4*)(Adst + s * 2048) = avr[s];
            *(int4*)(Wdst + s * 2048) = wvr[s];
        }
        __syncthreads();
        if (k0 + 64 < K) {
#pragma unroll
            for (int s = 0; s < 4; ++s) {
                avr[s] = *(const int4*)(Agp + k0 + 64 + (size_t)s * 32 * K);
                wvr[s] = *(const int4*)(Wgp + k0 + 64 + (size_t)s * 32 * K);
            }
        }
#pragma unroll
        for (int ks = 0; ks < 2; ++ks) {
            const int fcol = (ks * 32 + lhi * 8) ^ swz;
            bf16x8 af[4], bfm[4];
#pragma unroll
            for (int m = 0; m < 4; ++m)
                af[m] = *(const bf16x8*)(Afr + m * 1024 + fcol);
#pragma unroll
            for (int n = 0; n < 4; ++n)
                bfm[n] = *(const bf16x8*)(Wfr + n * 1024 + fcol);
#pragma unroll
            for (int m = 0; m < 4; ++m)
#pragma unroll
                for (int n = 0; n < 4; ++n)
                    acc[m][n] = __builtin_amdgcn_mfma_f32_16x16x32_bf16(
                        af[m], bfm[n], acc[m][n], 0, 0, 0);
        }
    }

    const int row0 = mbase + wr * 64 + lhi * 4;
    const int col0 = nbase + wc * 64 + l15;
#pragma unroll
    for (int m = 0; m < 4; ++m)
#pragma unroll
        for (int n = 0; n < 4; ++n) {
            int cc = col0 + n * 16;
#pragma unroll
            for (int r = 0; r < 4; ++r) {
                int rr = row0 + m * 16 + r;
                float v = acc[m][n][r];
                if (EPI == 1) {
                    v = fmaxf(v, 0.0f); v = v * v;
                    Cb[(size_t)rr * N + cc] = (ushort)f2bf(v);
                } else if (EPI == 2) {
                    Cb[(size_t)rr * N + cc] = (ushort)f2bf(v);
                } else {
                    Cf[(size_t)rr * N + cc] = v;
                }
            }
        }
}

// ---------------- per-head RMS + RoPE (+ optional q_gain), f32 in -> bf16 out ----------------
__global__ __launch_bounds__(256) void qknorm_kernel(const float* __restrict__ q,
                                                     ushort* __restrict__ qout,
                                                     const float* __restrict__ cosT,
                                                     const float* __restrict__ sinT,
                                                     const float* __restrict__ gain) {
    int gid = blockIdx.x * blockDim.x + threadIdx.x;
    int gw = gid >> 6, lane = gid & 63;
    int head = gw & (HH - 1);
    int c = (gw >> 4) & (CC - 1);
    int b = gw >> 14;
    size_t off = ((size_t)(b * CC + c)) * DD + head * HDIM + lane;
    float v = q[off];
    float ss = v * v;
    for (int o = 32; o; o >>= 1) ss += __shfl_xor(ss, o);
    float r = rsqrtf(ss * (1.0f / HDIM) + F32_EPS);
    float vn = v * r;
    float other = __shfl_xor(vn, 32);
    int i = lane & 31;
    float cv = cosT[c * 32 + i], sv = sinT[c * 32 + i];
    float out = (lane < 32) ? (vn * cv + other * sv) : (vn * cv - other * sv);
    if (gain) out *= gain[head];
    qout[off] = (ushort)f2bf(out);
}

// ---------------- bf16 MFMA causal flash attention ----------------
// Block = (qtile64, head, b); 4 waves, each owns 16 q rows. KV tiles of 64.
// All LDS tiles XOR-swizzled (T2) for conflict-free ds_read_b128 fragments.
__global__ __launch_bounds__(256) void attn_mfma(const ushort* __restrict__ q,
                                                 const ushort* __restrict__ k,
                                                 const ushort* __restrict__ v,
                                                 ushort* __restrict__ y) {
    __shared__ __align__(16) ushort Qs[64 * 64];  // [qrow][d  ^ sw(qrow)]
    __shared__ __align__(16) ushort Ks[64 * 64];  // [kv]  [d  ^ sw(kv)]
    __shared__ __align__(16) ushort VT[64 * 64];  // [d]   [kv ^ sw(d)]
    __shared__ __align__(16) ushort Ps[64 * 64];  // [qrow][kv ^ sw(qrow)] (wave-private rows)
    const int qt = blockIdx.x, head = blockIdx.y, b = blockIdx.z;
    const int tid = threadIdx.x;
    const int wid = tid >> 6, lane = tid & 63;
    const int l15 = lane & 15, lhi = lane >> 4;
    const int wq0 = wid * 16;
    const int qbase = qt * 64;

    const int srow = tid >> 3;            // 0..31
    const int scol = (tid & 7) * 8;       // 0..56 step 8

    // stage Q once
#pragma unroll
    for (int s = 0; s < 2; ++s) {
        int r = srow + s * 32;
        int4 t4 = *(const int4*)&q[((size_t)(b * CC + qbase + r)) * DD + head * HDIM + scol];
        *(int4*)&Qs[r * 64 + (scol ^ ((r & 7) << 3))] = t4;
    }

    f32x4 oacc[4] = {};
    float mrow[4] = {-INFINITY, -INFINITY, -INFINITY, -INFINITY};
    float lrow[4] = {0.f, 0.f, 0.f, 0.f};

    for (int kt = 0; kt <= qt; ++kt) {
        __syncthreads();   // prior iteration's fragment reads done
        // stage K tile and transposed V tile
#pragma unroll
        for (int s = 0; s < 2; ++s) {
            int r = srow + s * 32;
            size_t goff = ((size_t)(b * CC + kt * 64 + r)) * DD + head * HDIM + scol;
            int4 kv4 = *(const int4*)&k[goff];
            *(int4*)&Ks[r * 64 + (scol ^ ((r & 7) << 3))] = kv4;
            int4 vv4 = *(const int4*)&v[goff];
            const ushort* pv = (const ushort*)&vv4;
#pragma unroll
            for (int j = 0; j < 8; ++j) {
                int d = scol + j;
                VT[d * 64 + (r ^ ((d & 7) << 3))] = pv[j];
            }
        }
        __syncthreads();

        // QK^T: 16 q rows x 64 kv per wave
        f32x4 sac[4] = {};
#pragma unroll
        for (int ks = 0; ks < 2; ++ks) {
            int dcol = ks * 32 + lhi * 8;
            int arow = wq0 + l15;
            bf16x8 af = *(const bf16x8*)&Qs[arow * 64 + (dcol ^ ((arow & 7) << 3))];
#pragma unroll
            for (int n = 0; n < 4; ++n) {
                int krow = n * 16 + l15;
                bf16x8 bfr = *(const bf16x8*)&Ks[krow * 64 + (dcol ^ ((krow & 7) << 3))];
                sac[n] = __builtin_amdgcn_mfma_f32_16x16x32_bf16(af, bfr, sac[n], 0, 0, 0);
            }
        }

        // scale + causal mask + online softmax + P->LDS(bf16)
        const bool diag = (kt == qt);
#pragma unroll
        for (int r = 0; r < 4; ++r) {
            int qrow_l = wq0 + lhi * 4 + r;          // 0..63 within tile
            int qrow_g = qbase + qrow_l;
            float sv[4];
#pragma unroll
            for (int n = 0; n < 4; ++n) {
                float t = sac[n][r] * 0.125f;        // 1/sqrt(64)
                if (diag && (kt * 64 + n * 16 + l15) > qrow_g) t = -INFINITY;
                sv[n] = t;
            }
            float tmax = fmaxf(fmaxf(sv[0], sv[1]), fmaxf(sv[2], sv[3]));
#pragma unroll
            for (int off = 1; off < 16; off <<= 1) tmax = fmaxf(tmax, __shfl_xor(tmax, off));
            float mn = fmaxf(mrow[r], tmax);
            float al = __expf(mrow[r] - mn);
            float p0 = __expf(sv[0] - mn), p1 = __expf(sv[1] - mn);
            float p2 = __expf(sv[2] - mn), p3 = __expf(sv[3] - mn);
            float ts = p0 + p1 + p2 + p3;
#pragma unroll
            for (int off = 1; off < 16; off <<= 1) ts += __shfl_xor(ts, off);
            lrow[r] = lrow[r] * al + ts;
            mrow[r] = mn;
#pragma unroll
            for (int n = 0; n < 4; ++n) oacc[n][r] *= al;
            int pb = qrow_l * 64, sw = (qrow_l & 7) << 3;
            Ps[pb + ((l15)      ^ sw)] = (ushort)f2bf(p0);
            Ps[pb + ((16 + l15) ^ sw)] = (ushort)f2bf(p1);
            Ps[pb + ((32 + l15) ^ sw)] = (ushort)f2bf(p2);
            Ps[pb + ((48 + l15) ^ sw)] = (ushort)f2bf(p3);
        }

        // PV: o += P @ V  (P rows are wave-private; compiler orders LDS RAW)
#pragma unroll
        for (int ks = 0; ks < 2; ++ks) {
            int kcol = ks * 32 + lhi * 8;
            int arow = wq0 + l15;
            bf16x8 pf = *(const bf16x8*)&Ps[arow * 64 + (kcol ^ ((arow & 7) << 3))];
#pragma unroll
            for (int n = 0; n < 4; ++n) {
                int vrow = n * 16 + l15;             // d
                bf16x8 vf = *(const bf16x8*)&VT[vrow * 64 + (kcol ^ ((vrow & 7) << 3))];
                oacc[n] = __builtin_amdgcn_mfma_f32_16x16x32_bf16(pf, vf, oacc[n], 0, 0, 0);
            }
        }
    }

    // epilogue: divide by row sums, store bf16
#pragma unroll
    for (int r = 0; r < 4; ++r) {
        float inv = 1.0f / lrow[r];
        int qrow_g = qbase + wq0 + lhi * 4 + r;
        size_t base = ((size_t)(b * CC + qrow_g)) * DD + head * HDIM;
#pragma unroll
        for (int n = 0; n < 4; ++n)
            y[base + n * 16 + l15] = (ushort)f2bf(oacc[n][r] * inv);
    }
}

// ---------------- h += scale (.) a ----------------
__global__ void resid_kernel(float* __restrict__ h, const float* __restrict__ a,
                             const float* __restrict__ scale) {
    int idx = blockIdx.x * blockDim.x + threadIdx.x;   // per float4
    size_t off = (size_t)idx * 4;
    float4 hv = *(float4*)&h[off];
    float4 av = *(const float4*)&a[off];
    float4 sv = *(const float4*)&scale[(idx & 255) * 4];
    hv.x += sv.x * av.x; hv.y += sv.y * av.y;
    hv.z += sv.z * av.z; hv.w += sv.w * av.w;
    *(float4*)&h[off] = hv;
}

// ---------------- out = h * valid ----------------
__global__ void mask_kernel(const float* __restrict__ h, const int* __restrict__ nch,
                            float* __restrict__ out) {
    int idx = blockIdx.x * blockDim.x + threadIdx.x;   // per float4
    int c = (idx >> 8) & (CC - 1);
    int b = idx >> 18;
    float4 hv = *(const float4*)&h[(size_t)idx * 4];
    if (c >= nch[b]) hv = make_float4(0.f, 0.f, 0.f, 0.f);
    *(float4*)&out[(size_t)idx * 4] = hv;
}

extern "C" void kernel_launch(void* const* d_in, const int* in_sizes, int n_in,
                              void* d_out, int out_size, void* d_ws, size_t ws_size,
                              hipStream_t stream) {
    const float* x        = (const float*)d_in[0];
    const int*   boundary = (const int*)d_in[1];
    const float* Wq       = (const float*)d_in[2];
    const float* Wk       = (const float*)d_in[3];
    const float* Wv       = (const float*)d_in[4];
    const float* Wo       = (const float*)d_in[5];
    const float* qg       = (const float*)d_in[6];
    const float* fcw      = (const float*)d_in[7];
    const float* projw    = (const float*)d_in[8];
    const float* ascale   = (const float*)d_in[9];
    const float* mscale   = (const float*)d_in[10];
    const float* rmix     = (const float*)d_in[11];
    float* out = (float*)d_out;

    const size_t NTOK = (size_t)BB * CC * DD;           // 4M elems
    const size_t NHID = (size_t)BB * CC * DFF;          // 16M elems

    float* ws   = (float*)d_ws;
    float*  h    = ws;
    float*  x0   = h  + NTOK;
    float*  qb   = x0 + NTOK;                            // f32 q (pre-norm)
    float*  kb   = qb + NTOK;                            // f32 k (pre-norm)
    ushort* xnb  = (ushort*)(kb + NTOK);
    ushort* ybf  = xnb + NTOK;
    ushort* hidb = ybf + NTOK;           // 16M bf16; doubles as qbb/kbb/vbb during attn
    ushort* wbuf = hidb + NHID;          // 16M bf16 (reused for every weight matrix)
    float*  cosT = (float*)(wbuf + NHID);
    float*  sinT = cosT + (size_t)CC * 32;
    int*    starts = (int*)(sinT + (size_t)CC * 32);
    int*    nch    = starts + BB * (CC + 1);

    ushort* qbb = hidb;                  // bf16 q (post-norm)
    ushort* kbb = hidb + NTOK;           // bf16 k (post-norm)
    ushort* vbb = hidb + 2 * NTOK;       // bf16 v

    const int M = BB * CC;  // 4096 rows
    const int CAST_D2  = (int)(DD * DD / 8 / 256);
    const int CAST_DF  = (int)(DD * DFF / 8 / 256);

    rope_init_kernel<<<CC * 32 / 256, 256, 0, stream>>>(cosT, sinT);
    scan_kernel<<<BB, 1024, 0, stream>>>(boundary, starts, nch);
    latents_kernel<<<dim3(CC, BB), 256, 0, stream>>>(x, starts, h, x0);

    for (int l = 0; l < LL; ++l) {
        // h = mix0*h + mix1*x0 ; xnb = bf16(rms(h))
        rmsmix_kernel<<<M, 256, 0, stream>>>(h, x0, rmix + (size_t)l * 2 * DD, h, xnb);
        // QKV (bf16 MFMA; weights cast on demand into wbuf)
        cast_kernel<<<CAST_D2, 256, 0, stream>>>(Wq + (size_t)l * DD * DD, wbuf, DD * DD / 8);
        gemm_bf16<0><<<dim3(DD / 128, M / 128), 256, 0, stream>>>(xnb, wbuf, qb, nullptr, M, DD, DD);
        cast_kernel<<<CAST_D2, 256, 0, stream>>>(Wk + (size_t)l * DD * DD, wbuf, DD * DD / 8);
        gemm_bf16<0><<<dim3(DD / 128, M / 128), 256, 0, stream>>>(xnb, wbuf, kb, nullptr, M, DD, DD);
        cast_kernel<<<CAST_D2, 256, 0, stream>>>(Wv + (size_t)l * DD * DD, wbuf, DD * DD / 8);
        gemm_bf16<2><<<dim3(DD / 128, M / 128), 256, 0, stream>>>(xnb, wbuf, nullptr, vbb, M, DD, DD);
        // per-head RMS + RoPE (+gain for q) -> bf16
        qknorm_kernel<<<(BB * CC * HH * 64) / 256, 256, 0, stream>>>(qb, qbb, cosT, sinT, qg + l * HH);
        qknorm_kernel<<<(BB * CC * HH * 64) / 256, 256, 0, stream>>>(kb, kbb, cosT, sinT, nullptr);
        // MFMA attention -> ybf (bf16)
        attn_mfma<<<dim3(16, HH, BB), 256, 0, stream>>>(qbb, kbb, vbb, ybf);
        // a = y @ Wo^T -> qb (f32)
        cast_kernel<<<CAST_D2, 256, 0, stream>>>(Wo + (size_t)l * DD * DD, wbuf, DD * DD / 8);
        gemm_bf16<0><<<dim3(DD / 128, M / 128), 256, 0, stream>>>(ybf, wbuf, qb, nullptr, M, DD, DD);
        resid_kernel<<<(int)(NTOK / 4 / 256), 256, 0, stream>>>(h, qb, ascale + l * DD);
        // MLP
        rmsmix_kernel<<<M, 256, 0, stream>>>(h, nullptr, nullptr, nullptr, xnb);
        cast_kernel<<<CAST_DF, 256, 0, stream>>>(fcw + (size_t)l * DFF * DD, wbuf, DD * DFF / 8);
        gemm_bf16<1><<<dim3(DFF / 128, M / 128), 256, 0, stream>>>(xnb, wbuf, nullptr, hidb, M, DFF, DD);
        cast_kernel<<<CAST_DF, 256, 0, stream>>>(projw + (size_t)l * DD * DFF, wbuf, DD * DFF / 8);
        gemm_bf16<0><<<dim3(DD / 128, M / 128), 256, 0, stream>>>(hidb, wbuf, qb, nullptr, M, DD, DFF);
        resid_kernel<<<(int)(NTOK / 4 / 256), 256, 0, stream>>>(h, qb, mscale + l * DD);
    }
    mask_kernel<<<(int)(NTOK / 4 / 256), 256, 0, stream>>>(h, nch, out);
}

// Round 4
// 1278.296 us; speedup vs baseline: 9.1822x; 2.0850x over previous
//
#include <hip/hip_runtime.h>
#include <math.h>

// Problem constants (fixed by reference)
#define BB   4
#define SS   4096
#define DD   1024
#define HH   16
#define HDIM 64
#define CC   1024      // MAX_CHUNKS
#define DFF  4096
#define LL   4

static constexpr float F32_EPS = 1.1920928955078125e-07f;  // jnp.finfo(f32).eps

typedef __attribute__((ext_vector_type(8))) __bf16 bf16x8;
typedef __attribute__((ext_vector_type(4))) float  f32x4;

__device__ __forceinline__ uint f2bf(float f) {
    uint u = __float_as_uint(f);
    return (u + 0x7fffu + ((u >> 16) & 1u)) >> 16;   // RNE
}

// direct global->LDS DMA, 16 bytes per lane; lds dest must be wave-uniform
__device__ __forceinline__ void gl_lds16(const ushort* g, ushort* l) {
    __builtin_amdgcn_global_load_lds(
        (const __attribute__((address_space(1))) unsigned int*)g,
        (__attribute__((address_space(3))) unsigned int*)l, 16, 0, 0);
}

// ---------------- f32 -> bf16 cast (8 elems/thread) ----------------
__global__ __launch_bounds__(256) void cast_kernel(const float* __restrict__ in,
                                                   ushort* __restrict__ out, int n8) {
    int i = blockIdx.x * blockDim.x + threadIdx.x;
    if (i >= n8) return;
    const float4* p = (const float4*)(in + (size_t)i * 8);
    float4 a = p[0], b = p[1];
    uint4 o;
    o.x = f2bf(a.x) | (f2bf(a.y) << 16);
    o.y = f2bf(a.z) | (f2bf(a.w) << 16);
    o.z = f2bf(b.x) | (f2bf(b.y) << 16);
    o.w = f2bf(b.z) | (f2bf(b.w) << 16);
    *(uint4*)(out + (size_t)i * 8) = o;
}

// cast Wq|Wk|Wv (each DD*DD) into one contiguous 3072xDD bf16 buffer
__global__ __launch_bounds__(256) void castqkv_kernel(const float* __restrict__ Wq,
                                                      const float* __restrict__ Wk,
                                                      const float* __restrict__ Wv,
                                                      ushort* __restrict__ out) {
    int i = blockIdx.x * blockDim.x + threadIdx.x;          // 0 .. 3*DD*DD/8
    const int SEG = DD * DD / 8;                            // 131072
    int seg = i / SEG, r = i - seg * SEG;
    const float* src = (seg == 0 ? Wq : (seg == 1 ? Wk : Wv)) + (size_t)r * 8;
    const float4* p = (const float4*)src;
    float4 a = p[0], b = p[1];
    uint4 o;
    o.x = f2bf(a.x) | (f2bf(a.y) << 16);
    o.y = f2bf(a.z) | (f2bf(a.w) << 16);
    o.z = f2bf(b.x) | (f2bf(b.y) << 16);
    o.w = f2bf(b.z) | (f2bf(b.w) << 16);
    *(uint4*)(out + (size_t)i * 8) = o;
}

// ---------------- RoPE tables ----------------
__global__ void rope_init_kernel(float* __restrict__ cosT, float* __restrict__ sinT) {
    int idx = blockIdx.x * blockDim.x + threadIdx.x;   // over CC*32
    int pos = idx >> 5;
    int i   = idx & 31;
    float inv = powf(10000.0f, -(float)i / 32.0f);
    float f = (float)pos * inv;
    cosT[idx] = cosf(f);
    sinT[idx] = sinf(f);
}

// ---------------- boundary scan -> chunk starts, num_chunks ----------------
__global__ __launch_bounds__(1024) void scan_kernel(const int* __restrict__ boundary,
                                                    int* __restrict__ starts,
                                                    int* __restrict__ nch) {
    __shared__ int tmp[1024];
    int b = blockIdx.x, t = threadIdx.x;
    int base = b * SS + t * 4;
    int v0 = boundary[base + 0], v1 = boundary[base + 1];
    int v2 = boundary[base + 2], v3 = boundary[base + 3];
    int p0 = v0, p1 = p0 + v1, p2 = p1 + v2, p3 = p2 + v3;
    tmp[t] = p3;
    __syncthreads();
    for (int off = 1; off < 1024; off <<= 1) {
        int add = (t >= off) ? tmp[t - off] : 0;
        __syncthreads();
        tmp[t] += add;
        __syncthreads();
    }
    int excl = tmp[t] - p3;
    if (v0) starts[b * (CC + 1) + (excl + p0 - 1)] = t * 4 + 0;
    if (v1) starts[b * (CC + 1) + (excl + p1 - 1)] = t * 4 + 1;
    if (v2) starts[b * (CC + 1) + (excl + p2 - 1)] = t * 4 + 2;
    if (v3) starts[b * (CC + 1) + (excl + p3 - 1)] = t * 4 + 3;
    int total = tmp[1023];
    if (t == 0) nch[b] = total;
    for (int c = t; c <= CC; c += 1024)
        if (c >= total) starts[b * (CC + 1) + c] = SS;
}

// ---------------- chunk means -> h and x0 ----------------
__global__ __launch_bounds__(256) void latents_kernel(const float* __restrict__ x,
                                                      const int* __restrict__ starts,
                                                      float* __restrict__ h,
                                                      float* __restrict__ x0) {
    int c = blockIdx.x, b = blockIdx.y, t = threadIdx.x;
    int s0 = starts[b * (CC + 1) + c];
    int s1 = starts[b * (CC + 1) + c + 1];
    float a0 = 0.f, a1 = 0.f, a2 = 0.f, a3 = 0.f;
    for (int r = s0; r < s1; ++r) {
        const float4 xv = *(const float4*)&x[((size_t)(b * SS + r)) * DD + t * 4];
        a0 += xv.x; a1 += xv.y; a2 += xv.z; a3 += xv.w;
    }
    float inv = (s1 > s0) ? 1.0f / (float)(s1 - s0) : 0.0f;
    float4 o = make_float4(a0 * inv, a1 * inv, a2 * inv, a3 * inv);
    size_t off = ((size_t)(b * CC + c)) * DD + t * 4;
    *(float4*)&h[off]  = o;
    *(float4*)&x0[off] = o;
}

// ---------------- optional resid-mix + row RMS norm, bf16 normed output ----------------
__global__ __launch_bounds__(256) void rmsmix_kernel(const float* __restrict__ hin,
                                                     const float* __restrict__ x0,
                                                     const float* __restrict__ mix,
                                                     float* __restrict__ hout,
                                                     ushort* __restrict__ xnout) {
    int row = blockIdx.x, t = threadIdx.x;
    size_t off = (size_t)row * DD + t * 4;
    float4 hv = *(const float4*)&hin[off];
    if (mix) {
        float4 m0 = *(const float4*)&mix[t * 4];
        float4 m1 = *(const float4*)&mix[DD + t * 4];
        float4 xv = *(const float4*)&x0[off];
        hv.x = m0.x * hv.x + m1.x * xv.x;
        hv.y = m0.y * hv.y + m1.y * xv.y;
        hv.z = m0.z * hv.z + m1.z * xv.z;
        hv.w = m0.w * hv.w + m1.w * xv.w;
    }
    float ss = hv.x * hv.x + hv.y * hv.y + hv.z * hv.z + hv.w * hv.w;
    for (int o = 32; o; o >>= 1) ss += __shfl_xor(ss, o);
    __shared__ float wsum[4];
    int lane = t & 63, wid = t >> 6;
    if (lane == 0) wsum[wid] = ss;
    __syncthreads();
    float tot = wsum[0] + wsum[1] + wsum[2] + wsum[3];
    float r = rsqrtf(tot * (1.0f / DD) + F32_EPS);
    if (hout) *(float4*)&hout[off] = hv;
    uint2 pk;
    pk.x = f2bf(hv.x * r) | (f2bf(hv.y * r) << 16);
    pk.y = f2bf(hv.z * r) | (f2bf(hv.w * r) << 16);
    *(uint2*)&xnout[off] = pk;
}

// ---------------- bf16 MFMA GEMM: C[M,N(slice)] = A[M,K] @ W[N,K]^T ----------------
// 128x128 tile, BK=64, 4 waves (2x2). Staging via global_load_lds width=16 with
// inverse-swizzled per-lane global source (linear LDS dest), swizzled ds_read_b128
// fragments (conflict-free). LDS content identical to proven reg-staged version.
// EPI 0: f32 store (+ blockIdx.z*partStride for split-K partials)
// EPI 1: relu(x)^2 bf16 store;  EPI 2: plain bf16 store
// EPI 3: fused-QKV routing: n<1024 -> Cf(f32), n<2048 -> Cf2(f32), else Cb(bf16); ldc=1024
template <int EPI>
__global__ __launch_bounds__(256) void gemm_bf16(const ushort* __restrict__ A,
                                                 const ushort* __restrict__ W,
                                                 float* __restrict__ Cf,
                                                 float* __restrict__ Cf2,
                                                 ushort* __restrict__ Cb,
                                                 int M, int N, int K, int lda, int ldw,
                                                 size_t partStride) {
    __shared__ __align__(16) ushort Als[128 * 64];
    __shared__ __align__(16) ushort Wls[128 * 64];
    const int tid  = threadIdx.x;
    const int wid  = tid >> 6, lane = tid & 63;
    const int wr   = wid >> 1, wc   = wid & 1;
    const int l15  = lane & 15, lhi = lane >> 4;
    const int mbase = blockIdx.y * 128, nbase = blockIdx.x * 128;

    A  += (size_t)blockIdx.z * K;          // split-K slice
    W  += (size_t)blockIdx.z * K;
    Cf += (size_t)blockIdx.z * partStride;

    // staging: wave w covers rows [w*32, w*32+32); per call s: 8 rows, 1KB LDS
    const int srow8  = lane >> 3;                       // 0..7 within 8-row group
    const int gchunk = ((lane & 7) ^ srow8) * 8;        // inverse-swizzled source chunk
    const ushort* Ag = A + (size_t)(mbase + wid * 32 + srow8) * lda + gchunk;
    const ushort* Wg = W + (size_t)(nbase + wid * 32 + srow8) * ldw + gchunk;
    ushort* Al = &Als[(wid * 32) * 64];                 // wave-uniform LDS bases
    ushort* Wl = &Wls[(wid * 32) * 64];

    f32x4 acc[4][4] = {};
    const int swz = (l15 & 7) << 3;
    const ushort* Afr = &Als[(wr * 64 + l15) * 64];
    const ushort* Wfr = &Wls[(wc * 64 + l15) * 64];

    for (int k0 = 0; k0 < K; k0 += 64) {
        __syncthreads();                                 // LDS reuse safe
#pragma unroll
        for (int s = 0; s < 4; ++s) {
            gl_lds16(Ag + k0 + (size_t)s * 8 * lda, Al + s * 8 * 64);
            gl_lds16(Wg + k0 + (size_t)s * 8 * ldw, Wl + s * 8 * 64);
        }
        __syncthreads();                                 // vmcnt(0) drained before barrier
#pragma unroll
        for (int ks = 0; ks < 2; ++ks) {
            const int fcol = (ks * 32 + lhi * 8) ^ swz;
            bf16x8 af[4], bfm[4];
#pragma unroll
            for (int m = 0; m < 4; ++m)
                af[m] = *(const bf16x8*)(Afr + m * 1024 + fcol);
#pragma unroll
            for (int n = 0; n < 4; ++n)
                bfm[n] = *(const bf16x8*)(Wfr + n * 1024 + fcol);
#pragma unroll
            for (int m = 0; m < 4; ++m)
#pragma unroll
                for (int n = 0; n < 4; ++n)
                    acc[m][n] = __builtin_amdgcn_mfma_f32_16x16x32_bf16(
                        af[m], bfm[n], acc[m][n], 0, 0, 0);
        }
    }

    // epilogue
    int   colb = nbase, ldc = N;
    float* fdst = Cf;
    ushort* bdst = Cb;
    if (EPI == 3) {
        ldc = 1024;
        if (nbase < 1024)      { fdst = Cf;  colb = nbase; }
        else if (nbase < 2048) { fdst = Cf2; colb = nbase - 1024; }
        else                   { fdst = nullptr; colb = nbase - 2048; }
    }
    const int row0 = mbase + wr * 64 + lhi * 4;
    const int col0 = colb + wc * 64 + l15;
#pragma unroll
    for (int m = 0; m < 4; ++m)
#pragma unroll
        for (int n = 0; n < 4; ++n) {
            int cc = col0 + n * 16;
#pragma unroll
            for (int r = 0; r < 4; ++r) {
                int rr = row0 + m * 16 + r;
                float v = acc[m][n][r];
                if (EPI == 0) {
                    fdst[(size_t)rr * ldc + cc] = v;
                } else if (EPI == 1) {
                    v = fmaxf(v, 0.0f); v = v * v;
                    bdst[(size_t)rr * ldc + cc] = (ushort)f2bf(v);
                } else if (EPI == 2) {
                    bdst[(size_t)rr * ldc + cc] = (ushort)f2bf(v);
                } else {
                    if (fdst) fdst[(size_t)rr * 1024 + cc] = v;
                    else      bdst[(size_t)rr * 1024 + cc] = (ushort)f2bf(v);
                }
            }
        }
}

// ---------------- per-head RMS + RoPE (+ optional q_gain), f32 in -> bf16 out ----------------
__global__ __launch_bounds__(256) void qknorm_kernel(const float* __restrict__ q,
                                                     ushort* __restrict__ qout,
                                                     const float* __restrict__ cosT,
                                                     const float* __restrict__ sinT,
                                                     const float* __restrict__ gain) {
    int gid = blockIdx.x * blockDim.x + threadIdx.x;
    int gw = gid >> 6, lane = gid & 63;
    int head = gw & (HH - 1);
    int c = (gw >> 4) & (CC - 1);
    int b = gw >> 14;
    size_t off = ((size_t)(b * CC + c)) * DD + head * HDIM + lane;
    float v = q[off];
    float ss = v * v;
    for (int o = 32; o; o >>= 1) ss += __shfl_xor(ss, o);
    float r = rsqrtf(ss * (1.0f / HDIM) + F32_EPS);
    float vn = v * r;
    float other = __shfl_xor(vn, 32);
    int i = lane & 31;
    float cv = cosT[c * 32 + i], sv = sinT[c * 32 + i];
    float out = (lane < 32) ? (vn * cv + other * sv) : (vn * cv - other * sv);
    if (gain) out *= gain[head];
    qout[off] = (ushort)f2bf(out);
}

// ---------------- bf16 MFMA causal flash attention ----------------
__global__ __launch_bounds__(256) void attn_mfma(const ushort* __restrict__ q,
                                                 const ushort* __restrict__ k,
                                                 const ushort* __restrict__ v,
                                                 ushort* __restrict__ y) {
    __shared__ __align__(16) ushort Qs[64 * 64];
    __shared__ __align__(16) ushort Ks[64 * 64];
    __shared__ __align__(16) ushort VT[64 * 64];
    __shared__ __align__(16) ushort Ps[64 * 64];
    const int qt = blockIdx.x, head = blockIdx.y, b = blockIdx.z;
    const int tid = threadIdx.x;
    const int wid = tid >> 6, lane = tid & 63;
    const int l15 = lane & 15, lhi = lane >> 4;
    const int wq0 = wid * 16;
    const int qbase = qt * 64;

    const int srow = tid >> 3;            // 0..31
    const int scol = (tid & 7) * 8;       // 0..56 step 8

#pragma unroll
    for (int s = 0; s < 2; ++s) {
        int r = srow + s * 32;
        int4 t4 = *(const int4*)&q[((size_t)(b * CC + qbase + r)) * DD + head * HDIM + scol];
        *(int4*)&Qs[r * 64 + (scol ^ ((r & 7) << 3))] = t4;
    }

    f32x4 oacc[4] = {};
    float mrow[4] = {-INFINITY, -INFINITY, -INFINITY, -INFINITY};
    float lrow[4] = {0.f, 0.f, 0.f, 0.f};

    for (int kt = 0; kt <= qt; ++kt) {
        __syncthreads();
#pragma unroll
        for (int s = 0; s < 2; ++s) {
            int r = srow + s * 32;
            size_t goff = ((size_t)(b * CC + kt * 64 + r)) * DD + head * HDIM + scol;
            int4 kv4 = *(const int4*)&k[goff];
            *(int4*)&Ks[r * 64 + (scol ^ ((r & 7) << 3))] = kv4;
            int4 vv4 = *(const int4*)&v[goff];
            const ushort* pv = (const ushort*)&vv4;
#pragma unroll
            for (int j = 0; j < 8; ++j) {
                int d = scol + j;
                VT[d * 64 + (r ^ ((d & 7) << 3))] = pv[j];
            }
        }
        __syncthreads();

        f32x4 sac[4] = {};
#pragma unroll
        for (int ks = 0; ks < 2; ++ks) {
            int dcol = ks * 32 + lhi * 8;
            int arow = wq0 + l15;
            bf16x8 af = *(const bf16x8*)&Qs[arow * 64 + (dcol ^ ((arow & 7) << 3))];
#pragma unroll
            for (int n = 0; n < 4; ++n) {
                int krow = n * 16 + l15;
                bf16x8 bfr = *(const bf16x8*)&Ks[krow * 64 + (dcol ^ ((krow & 7) << 3))];
                sac[n] = __builtin_amdgcn_mfma_f32_16x16x32_bf16(af, bfr, sac[n], 0, 0, 0);
            }
        }

        const bool diag = (kt == qt);
#pragma unroll
        for (int r = 0; r < 4; ++r) {
            int qrow_l = wq0 + lhi * 4 + r;
            int qrow_g = qbase + qrow_l;
            float sv[4];
#pragma unroll
            for (int n = 0; n < 4; ++n) {
                float t = sac[n][r] * 0.125f;
                if (diag && (kt * 64 + n * 16 + l15) > qrow_g) t = -INFINITY;
                sv[n] = t;
            }
            float tmax = fmaxf(fmaxf(sv[0], sv[1]), fmaxf(sv[2], sv[3]));
#pragma unroll
            for (int off = 1; off < 16; off <<= 1) tmax = fmaxf(tmax, __shfl_xor(tmax, off));
            float mn = fmaxf(mrow[r], tmax);
            float al = __expf(mrow[r] - mn);
            float p0 = __expf(sv[0] - mn), p1 = __expf(sv[1] - mn);
            float p2 = __expf(sv[2] - mn), p3 = __expf(sv[3] - mn);
            float ts = p0 + p1 + p2 + p3;
#pragma unroll
            for (int off = 1; off < 16; off <<= 1) ts += __shfl_xor(ts, off);
            lrow[r] = lrow[r] * al + ts;
            mrow[r] = mn;
#pragma unroll
            for (int n = 0; n < 4; ++n) oacc[n][r] *= al;
            int pb = qrow_l * 64, sw = (qrow_l & 7) << 3;
            Ps[pb + ((l15)      ^ sw)] = (ushort)f2bf(p0);
            Ps[pb + ((16 + l15) ^ sw)] = (ushort)f2bf(p1);
            Ps[pb + ((32 + l15) ^ sw)] = (ushort)f2bf(p2);
            Ps[pb + ((48 + l15) ^ sw)] = (ushort)f2bf(p3);
        }

#pragma unroll
        for (int ks = 0; ks < 2; ++ks) {
            int kcol = ks * 32 + lhi * 8;
            int arow = wq0 + l15;
            bf16x8 pf = *(const bf16x8*)&Ps[arow * 64 + (kcol ^ ((arow & 7) << 3))];
#pragma unroll
            for (int n = 0; n < 4; ++n) {
                int vrow = n * 16 + l15;
                bf16x8 vf = *(const bf16x8*)&VT[vrow * 64 + (kcol ^ ((vrow & 7) << 3))];
                oacc[n] = __builtin_amdgcn_mfma_f32_16x16x32_bf16(pf, vf, oacc[n], 0, 0, 0);
            }
        }
    }

#pragma unroll
    for (int r = 0; r < 4; ++r) {
        float inv = 1.0f / lrow[r];
        int qrow_g = qbase + wq0 + lhi * 4 + r;
        size_t base = ((size_t)(b * CC + qrow_g)) * DD + head * HDIM;
#pragma unroll
        for (int n = 0; n < 4; ++n)
            y[base + n * 16 + l15] = (ushort)f2bf(oacc[n][r] * inv);
    }
}

// ---------------- h += scale (.) (a0 [+ a1]) ----------------
template <int NP>
__global__ void resid_kernel(float* __restrict__ h, const float* __restrict__ a0,
                             const float* __restrict__ a1,
                             const float* __restrict__ scale) {
    int idx = blockIdx.x * blockDim.x + threadIdx.x;   // per float4
    size_t off = (size_t)idx * 4;
    float4 hv = *(float4*)&h[off];
    float4 av = *(const float4*)&a0[off];
    if (NP == 2) {
        float4 bv = *(const float4*)&a1[off];
        av.x += bv.x; av.y += bv.y; av.z += bv.z; av.w += bv.w;
    }
    float4 sv = *(const float4*)&scale[(idx & 255) * 4];
    hv.x += sv.x * av.x; hv.y += sv.y * av.y;
    hv.z += sv.z * av.z; hv.w += sv.w * av.w;
    *(float4*)&h[off] = hv;
}

// ---------------- out = h * valid ----------------
__global__ void mask_kernel(const float* __restrict__ h, const int* __restrict__ nch,
                            float* __restrict__ out) {
    int idx = blockIdx.x * blockDim.x + threadIdx.x;   // per float4
    int c = (idx >> 8) & (CC - 1);
    int b = idx >> 18;
    float4 hv = *(const float4*)&h[(size_t)idx * 4];
    if (c >= nch[b]) hv = make_float4(0.f, 0.f, 0.f, 0.f);
    *(float4*)&out[(size_t)idx * 4] = hv;
}

extern "C" void kernel_launch(void* const* d_in, const int* in_sizes, int n_in,
                              void* d_out, int out_size, void* d_ws, size_t ws_size,
                              hipStream_t stream) {
    const float* x        = (const float*)d_in[0];
    const int*   boundary = (const int*)d_in[1];
    const float* Wq       = (const float*)d_in[2];
    const float* Wk       = (const float*)d_in[3];
    const float* Wv       = (const float*)d_in[4];
    const float* Wo       = (const float*)d_in[5];
    const float* qg       = (const float*)d_in[6];
    const float* fcw      = (const float*)d_in[7];
    const float* projw    = (const float*)d_in[8];
    const float* ascale   = (const float*)d_in[9];
    const float* mscale   = (const float*)d_in[10];
    const float* rmix     = (const float*)d_in[11];
    float* out = (float*)d_out;

    const size_t NTOK = (size_t)BB * CC * DD;           // 4M elems
    const size_t NHID = (size_t)BB * CC * DFF;          // 16M elems

    float* ws   = (float*)d_ws;
    float*  h    = ws;
    float*  x0   = h  + NTOK;
    float*  qb   = x0 + NTOK;            // f32 q (pre-norm) / split-K partial 0
    float*  kb   = qb + NTOK;            // f32 k (pre-norm) / split-K partial 1 (contiguous!)
    ushort* xnb  = (ushort*)(kb + NTOK);
    ushort* ybf  = xnb + NTOK;
    ushort* hidb = ybf + NTOK;           // 16M bf16; doubles as qbb/kbb/vbb during attn
    ushort* wbuf = hidb + NHID;          // 16M bf16 (reused for every weight matrix)
    float*  cosT = (float*)(wbuf + NHID);
    float*  sinT = cosT + (size_t)CC * 32;
    int*    starts = (int*)(sinT + (size_t)CC * 32);
    int*    nch    = starts + BB * (CC + 1);

    ushort* qbb = hidb;                  // bf16 q (post-norm)
    ushort* kbb = hidb + NTOK;           // bf16 k (post-norm)
    ushort* vbb = hidb + 2 * NTOK;       // bf16 v

    const int M = BB * CC;  // 4096 rows
    const int CAST_D2  = (int)(DD * DD / 8 / 256);
    const int CAST_DF  = (int)(DD * DFF / 8 / 256);
    const int CAST_Q3  = (int)(3 * DD * DD / 8 / 256);

    rope_init_kernel<<<CC * 32 / 256, 256, 0, stream>>>(cosT, sinT);
    scan_kernel<<<BB, 1024, 0, stream>>>(boundary, starts, nch);
    latents_kernel<<<dim3(CC, BB), 256, 0, stream>>>(x, starts, h, x0);

    for (int l = 0; l < LL; ++l) {
        // h = mix0*h + mix1*x0 ; xnb = bf16(rms(h))
        rmsmix_kernel<<<M, 256, 0, stream>>>(h, x0, rmix + (size_t)l * 2 * DD, h, xnb);
        // fused QKV: C[M,3072] routed -> qb(f32), kb(f32), vbb(bf16)
        castqkv_kernel<<<CAST_Q3, 256, 0, stream>>>(Wq + (size_t)l * DD * DD,
                                                    Wk + (size_t)l * DD * DD,
                                                    Wv + (size_t)l * DD * DD, wbuf);
        gemm_bf16<3><<<dim3(3 * DD / 128, M / 128, 1), 256, 0, stream>>>(
            xnb, wbuf, qb, kb, vbb, M, 3 * DD, DD, DD, DD, 0);
        // per-head RMS + RoPE (+gain for q) -> bf16
        qknorm_kernel<<<(BB * CC * HH * 64) / 256, 256, 0, stream>>>(qb, qbb, cosT, sinT, qg + l * HH);
        qknorm_kernel<<<(BB * CC * HH * 64) / 256, 256, 0, stream>>>(kb, kbb, cosT, sinT, nullptr);
        // MFMA attention -> ybf (bf16)
        attn_mfma<<<dim3(16, HH, BB), 256, 0, stream>>>(qbb, kbb, vbb, ybf);
        // a = y @ Wo^T, split-K=2 -> partials qb,kb; h += ascale*(qb+kb)
        cast_kernel<<<CAST_D2, 256, 0, stream>>>(Wo + (size_t)l * DD * DD, wbuf, DD * DD / 8);
        gemm_bf16<0><<<dim3(DD / 128, M / 128, 2), 256, 0, stream>>>(
            ybf, wbuf, qb, nullptr, nullptr, M, DD, DD / 2, DD, DD, NTOK);
        resid_kernel<2><<<(int)(NTOK / 4 / 256), 256, 0, stream>>>(h, qb, kb, ascale + l * DD);
        // MLP
        rmsmix_kernel<<<M, 256, 0, stream>>>(h, nullptr, nullptr, nullptr, xnb);
        cast_kernel<<<CAST_DF, 256, 0, stream>>>(fcw + (size_t)l * DFF * DD, wbuf, DD * DFF / 8);
        gemm_bf16<1><<<dim3(DFF / 128, M / 128, 1), 256, 0, stream>>>(
            xnb, wbuf, nullptr, nullptr, hidb, M, DFF, DD, DD, DD, 0);
        cast_kernel<<<CAST_DF, 256, 0, stream>>>(projw + (size_t)l * DD * DFF, wbuf, DD * DFF / 8);
        gemm_bf16<0><<<dim3(DD / 128, M / 128, 2), 256, 0, stream>>>(
            hidb, wbuf, qb, nullptr, nullptr, M, DD, DFF / 2, DFF, DFF, NTOK);
        resid_kernel<2><<<(int)(NTOK / 4 / 256), 256, 0, stream>>>(h, qb, kb, mscale + l * DD);
    }
    mask_kernel<<<(int)(NTOK / 4 / 256), 256, 0, stream>>>(h, nch, out);
}